// Round 5
// baseline (558.466 us; speedup 1.0000x reference)
//
#include <hip/hip_runtime.h>

typedef __bf16 bf16x8 __attribute__((ext_vector_type(8)));
typedef float f32x4 __attribute__((ext_vector_type(4)));

// Raw barrier WITHOUT the vmcnt(0) drain that __syncthreads() emits.
#define FAST_BARRIER()                                        \
  do {                                                        \
    asm volatile("s_waitcnt lgkmcnt(0)" ::: "memory");        \
    __builtin_amdgcn_s_barrier();                             \
    asm volatile("" ::: "memory");                            \
  } while (0)

static __device__ __forceinline__ unsigned short f2bf(float f) {
  union { float fv; unsigned u; } v; v.fv = f;
  unsigned u = v.u;
  u += 0x7fffu + ((u >> 16) & 1u);   // round-to-nearest-even
  return (unsigned short)(u >> 16);
}

static __device__ __forceinline__ float fast_tanh(float x) {
  x = fminf(fmaxf(x, -15.f), 15.f);
  float ex = __expf(2.f * x);
  return (ex - 1.f) / (ex + 1.f);
}

// 8x fp32 -> bf16x8 via native casts (compiler emits v_cvt_pk_bf16_f32, RNE)
static __device__ __forceinline__ bf16x8 cvt8(const float4& a, const float4& b) {
  bf16x8 r;
  r[0] = (__bf16)a.x; r[1] = (__bf16)a.y; r[2] = (__bf16)a.z; r[3] = (__bf16)a.w;
  r[4] = (__bf16)b.x; r[5] = (__bf16)b.y; r[6] = (__bf16)b.z; r[7] = (__bf16)b.w;
  return r;
}

// ---- pack W (K x 512) fp32 row-major -> bf16 fragment-major P[k/8][n][k%8] ----
__global__ __launch_bounds__(256) void pack_all(
    const float* __restrict__ W1, const float* __restrict__ W2,
    const float* __restrict__ W3,
    unsigned short* __restrict__ W1p, unsigned short* __restrict__ W2p,
    unsigned short* __restrict__ W3p) {
  __shared__ float tile[32][65];
  const int N = 512;
  const float* W; unsigned short* P; int nk;
  if (blockIdx.z == 0)      { W = W1; P = W1p; nk = 64; }
  else if (blockIdx.z == 1) { W = W2; P = W2p; nk = 16; }
  else                      { W = W3; P = W3p; nk = 80; }
  if ((int)blockIdx.x >= nk) return;
  int k0 = blockIdx.x * 32, n0 = blockIdx.y * 64;
  int t = threadIdx.x;
  int nn = t & 63, kkb = t >> 6;
#pragma unroll
  for (int i = 0; i < 8; ++i) {
    int kk = kkb + i * 4;
    tile[kk][nn] = W[(size_t)(k0 + kk) * N + n0 + nn];
  }
  __syncthreads();
#pragma unroll
  for (int i = 0; i < 8; ++i) {
    int e = t + i * 256;                 // 0..2047
    int k8 = e & 7, n = (e >> 3) & 63, c = e >> 9;   // c = k-chunk within 32 (0..3)
    size_t dst = (size_t)((k0 >> 3) + c) * 4096 + (size_t)(n0 + n) * 8 + k8;
    P[dst] = f2bf(tile[c * 8 + k8][n]);
  }
}

// ---- per-batch prep (512 thr): gauss mask, tanh(hidden) into A2 cols 2048..2559 ----
__global__ __launch_bounds__(512) void prep_batch(
    const float* __restrict__ hidden,
    const float* __restrict__ ka1, const float* __restrict__ kb1,
    const float* __restrict__ ka2, const float* __restrict__ kb2,
    float* __restrict__ gauss,
    unsigned short* __restrict__ A2) {
  int b = blockIdx.x, t = threadIdx.x;
  __shared__ float hl[512];
  __shared__ float part[512];
  __shared__ float tt[128];
  __shared__ float pp[128];
  {
    float v = hidden[b * 512 + t];
    hl[t] = v;
    A2[(size_t)b * 2560 + 2048 + t] = f2bf(tanhf(v));
  }
  __syncthreads();
  {
    // 4-way split of the 512-MAC dot: ka1 for t<256, ka2 for t>=256
    const float* ka = (t < 256) ? ka1 : ka2;   // (512, 64)
    int lp = t & 63;
    int h0 = ((t >> 6) & 3) * 128;
    float s0 = 0.f, s1 = 0.f, s2 = 0.f, s3 = 0.f;
    for (int h = h0; h < h0 + 128; h += 4) {
      s0 += hl[h + 0] * ka[(h + 0) * 64 + lp];
      s1 += hl[h + 1] * ka[(h + 1) * 64 + lp];
      s2 += hl[h + 2] * ka[(h + 2) * 64 + lp];
      s3 += hl[h + 3] * ka[(h + 3) * 64 + lp];
    }
    part[t] = (s0 + s1) + (s2 + s3);
  }
  __syncthreads();
  if (t < 128) {
    int base = ((t >= 64) ? 256 : 0) + (t & 63);
    tt[t] = tanhf(part[base] + part[base + 64] + part[base + 128] + part[base + 192]);
  }
  __syncthreads();
  if (t < 128) {
    const float* kb = (t < 64) ? kb1 : kb2;   // (64, 64)
    const float* ts = (t < 64) ? tt : tt + 64;
    int l = t & 63;
    float s = 0.f;
    for (int j = 0; j < 64; ++j) s += ts[j] * kb[j * 64 + l];
    pp[t] = 8.0f / (1.0f + expf(-s));         // sigmoid * sqrt(64)
  }
  __syncthreads();
  if (t < 64) {
    float fi = (float)(t + 1);
    float r = floorf(fi * 0.125f);
    float c = floorf(fmodf(fi, 8.0f)) - 1.0f;
    float dr = r - pp[t], dc = c - pp[64 + t];
    gauss[b * 64 + t] = expf(-2.0f * (dr * dr + dc * dc));
  }
}

// ---- 64x64-tile bf16 MFMA GEMM, B direct from L2 fragment-layout, K-split ----
__global__ __launch_bounds__(256, 4) void gemm64d(
    const unsigned short* __restrict__ A, int lda, int k8_stride, int nsteps,
    const unsigned short* __restrict__ Wp,
    const float* __restrict__ bias,
    float* __restrict__ C) {
  __shared__ unsigned short lA[64 * 40];
  int m0 = blockIdx.x * 64, n0 = blockIdx.y * 64;
  int z = blockIdx.z;
  int k8 = z * k8_stride;
  int t = threadIdx.x;
  int w = t >> 6, lane = t & 63, q = lane >> 4, l15 = lane & 15;
  f32x4 acc[4] = {};
  int arow = t >> 2, achk = (t & 3) * 8;
  const unsigned short* pA = A + (size_t)(m0 + arow) * lda + (size_t)k8 * 8 + achk;
  const unsigned short* pB = Wp + ((size_t)(k8 + q) * 512 + n0 + w * 16 + l15) * 8;
  int4 av = *(const int4*)(pA);
  int4 bv = *(const int4*)(pB);
  for (int ks = 0; ks < nsteps; ++ks) {
    FAST_BARRIER();
    *(int4*)(lA + arow * 40 + achk) = av;
    FAST_BARRIER();
    int ksn = (ks + 1 < nsteps) ? ks + 1 : ks;
    av = *(const int4*)(pA + ksn * 32);
    int4 bn = *(const int4*)(pB + (size_t)ksn * 16384);
    bf16x8 bf = *(const bf16x8*)&bv;
#pragma unroll
    for (int mt = 0; mt < 4; ++mt) {
      bf16x8 af = *(const bf16x8*)(lA + (mt * 16 + l15) * 40 + q * 8);
      acc[mt] = __builtin_amdgcn_mfma_f32_16x16x32_bf16(af, bf, acc[mt], 0, 0, 0);
    }
    bv = bn;
  }
  int col = n0 + w * 16 + l15;
  if (bias) {
    float bsv = bias[col];
#pragma unroll
    for (int mt = 0; mt < 4; ++mt)
#pragma unroll
      for (int j = 0; j < 4; ++j)
        C[(size_t)(m0 + mt * 16 + q * 4 + j) * 512 + col] = acc[mt][j] + bsv;
  } else {
    float* Cp = C + (size_t)z * 262144;
#pragma unroll
    for (int mt = 0; mt < 4; ++mt)
#pragma unroll
      for (int j = 0; j < 4; ++j)
        Cp[(size_t)(m0 + mt * 16 + q * 4 + j) * 512 + col] = acc[mt][j];
  }
}

// ---- reduce 4 K-split partials + bias -> out ----
__global__ __launch_bounds__(256) void reduce4(const float* __restrict__ part,
                                               const float* __restrict__ b3,
                                               float* __restrict__ out) {
  int i = blockIdx.x * 256 + threadIdx.x;   // float4 index, 65536 total
  int base = i * 4;
  int n = base & 511;
  float4 p0 = *(const float4*)(part + base);
  float4 p1 = *(const float4*)(part + 262144 + base);
  float4 p2 = *(const float4*)(part + 524288 + base);
  float4 p3 = *(const float4*)(part + 786432 + base);
  float4 bv = *(const float4*)(b3 + n);
  float4 r;
  r.x = p0.x + p1.x + p2.x + p3.x + bv.x;
  r.y = p0.y + p1.y + p2.y + p3.y + bv.y;
  r.z = p0.z + p1.z + p2.z + p3.z + bv.z;
  r.w = p0.w + p1.w + p2.w + p3.w + bv.w;
  *(float4*)(out + base) = r;
}

// ---- fused attn v2h: BARRIER-FREE K-loop, A direct from global (no LDS tile) ----
// one block per batch, 256 thr (4 waves). Wave w owns U-cols [w*128, w*128+128).
// K extended to 2560: phases 0..63 = feat@W1 (k=2048), phases 64..79 = h@W2
// (W2p sits contiguously at W1p+2MB with identical packed layout).
// A (HBM): 1-phase register prefetch. B (W1p, L2-resident): loaded in-phase —
// keeps register demand ~220 < 256 cap (no spill; round-4 version spilled).
__global__ __launch_bounds__(256, 2) void attn_main(
    const float* __restrict__ feat,          // (B*64, 2048) fp32
    const unsigned short* __restrict__ W1p,  // bf16 fragment-major, W2p contiguous after
    const float* __restrict__ b1,
    const float* __restrict__ b2,
    const float* __restrict__ hidden,        // (512, 512) fp32
    const float* __restrict__ V,
    const float* __restrict__ bVp,
    const float* __restrict__ gauss,
    float* __restrict__ aw_out,
    unsigned short* __restrict__ A2) {
  __shared__ float red[64 * 4];
  __shared__ float awl[64];
  int b = blockIdx.x, t = threadIdx.x;
  int w = t >> 6, lane = t & 63, q = lane >> 4, l15 = lane & 15;
  f32x4 acc[4][8] = {};
  const float* Ab = feat + (size_t)b * (64 * 2048);
  const float* pAr = Ab + l15 * 2048 + q * 8;          // + mt*32768 + s*32
  const float* ph  = hidden + b * 512 + q * 8;         // + s2*32 (broadcast rows)
  const unsigned short* pB = W1p + ((size_t)q * 512 + w * 128 + l15) * 8;

  // preamble: phase-0 A into regs
  float4 fc[8];
#pragma unroll
  for (int mt = 0; mt < 4; ++mt) {
    fc[2 * mt]     = *(const float4*)(pAr + mt * 32768);
    fc[2 * mt + 1] = *(const float4*)(pAr + mt * 32768 + 4);
  }
  bf16x8 af[4];
#pragma unroll
  for (int mt = 0; mt < 4; ++mt) af[mt] = cvt8(fc[2 * mt], fc[2 * mt + 1]);

  // main loop: feat phases 0..63 (k = s*32); no barriers, waves drift freely
  for (int s = 0; s < 64; ++s) {
    int kf = (s + 1 < 64) ? s + 1 : 63;
    float4 fn[8];
    const float* ap = pAr + kf * 32;
#pragma unroll
    for (int mt = 0; mt < 4; ++mt) {
      fn[2 * mt]     = *(const float4*)(ap + mt * 32768);
      fn[2 * mt + 1] = *(const float4*)(ap + mt * 32768 + 4);
    }
    const unsigned short* bp = pB + (size_t)s * 16384;
    int4 bc[8];
#pragma unroll
    for (int nt = 0; nt < 8; ++nt) bc[nt] = *(const int4*)(bp + nt * 128);
#pragma unroll
    for (int mt = 0; mt < 4; ++mt)
#pragma unroll
      for (int nt = 0; nt < 8; ++nt)
        acc[mt][nt] = __builtin_amdgcn_mfma_f32_16x16x32_bf16(
            af[mt], *(const bf16x8*)&bc[nt], acc[mt][nt], 0, 0, 0);
#pragma unroll
    for (int mt = 0; mt < 4; ++mt) af[mt] = cvt8(fn[2 * mt], fn[2 * mt + 1]);
  }

  // tail: h@W2 phases 64..79; A-frag is row-broadcast hidden chunk (same for all mt)
  for (int s2 = 0; s2 < 16; ++s2) {
    float4 ha  = *(const float4*)(ph + s2 * 32);
    float4 hb4 = *(const float4*)(ph + s2 * 32 + 4);
    const unsigned short* bp = pB + (size_t)(64 + s2) * 16384;
    int4 bt[8];
#pragma unroll
    for (int nt = 0; nt < 8; ++nt) bt[nt] = *(const int4*)(bp + nt * 128);
    bf16x8 ah = cvt8(ha, hb4);
#pragma unroll
    for (int mt = 0; mt < 4; ++mt)
#pragma unroll
      for (int nt = 0; nt < 8; ++nt)
        acc[mt][nt] = __builtin_amdgcn_mfma_f32_16x16x32_bf16(
            ah, *(const bf16x8*)&bt[nt], acc[mt][nt], 0, 0, 0);
  }

  // epilogue operands (tiny, L2-resident)
  float vv[8], bb[8];
#pragma unroll
  for (int nt = 0; nt < 8; ++nt) {
    int u = w * 128 + nt * 16 + l15;
    vv[nt] = V[u];
    bb[nt] = b1[u] + b2[u];
  }
  float gs = (t < 64) ? gauss[b * 64 + t] : 0.f;
  float bV0 = bVp[0];

  // logits = sum_u tanh(acc + b1 + b2) * V[u]
#pragma unroll
  for (int mt = 0; mt < 4; ++mt) {
#pragma unroll
    for (int j = 0; j < 4; ++j) {
      float p = 0.f;
#pragma unroll
      for (int nt = 0; nt < 8; ++nt)
        p += fast_tanh(acc[mt][nt][j] + bb[nt]) * vv[nt];
      p += __shfl_xor(p, 1);
      p += __shfl_xor(p, 2);
      p += __shfl_xor(p, 4);
      p += __shfl_xor(p, 8);
      if (l15 == 0) red[(mt * 16 + q * 4 + j) * 4 + w] = p;
    }
  }
  __syncthreads();
  if (t < 64) {   // wave 0: softmax over L=64 + gaussian mask
    float s = bV0 + red[t * 4] + red[t * 4 + 1] + red[t * 4 + 2] + red[t * 4 + 3];
    float mx = s;
#pragma unroll
    for (int o = 1; o < 64; o <<= 1) mx = fmaxf(mx, __shfl_xor(mx, o));
    float e = __expf(s - mx);
    float sm = e;
#pragma unroll
    for (int o = 1; o < 64; o <<= 1) sm += __shfl_xor(sm, o);
    float a = (e / sm) * gs;
    awl[t] = a;
    aw_out[b * 64 + t] = a;
  }
  __syncthreads();
  // context: 8 cols per thread; write tanh(ctx) bf16 into A2
  float4 c0 = make_float4(0.f, 0.f, 0.f, 0.f);
  float4 c1 = make_float4(0.f, 0.f, 0.f, 0.f);
  const float* pF = Ab + t * 8;
  for (int l = 0; l < 64; ++l) {
    float a = awl[l];
    float4 g0 = *(const float4*)(pF + l * 2048);
    float4 g1 = *(const float4*)(pF + l * 2048 + 4);
    c0.x += a * g0.x; c0.y += a * g0.y; c0.z += a * g0.z; c0.w += a * g0.w;
    c1.x += a * g1.x; c1.y += a * g1.y; c1.z += a * g1.z; c1.w += a * g1.w;
  }
  ushort4 o0, o1;
  o0.x = f2bf(fast_tanh(c0.x)); o0.y = f2bf(fast_tanh(c0.y));
  o0.z = f2bf(fast_tanh(c0.z)); o0.w = f2bf(fast_tanh(c0.w));
  o1.x = f2bf(fast_tanh(c1.x)); o1.y = f2bf(fast_tanh(c1.y));
  o1.z = f2bf(fast_tanh(c1.z)); o1.w = f2bf(fast_tanh(c1.w));
  *(ushort4*)(A2 + (size_t)b * 2560 + t * 8) = o0;
  *(ushort4*)(A2 + (size_t)b * 2560 + t * 8 + 4) = o1;
}

extern "C" void kernel_launch(void* const* d_in, const int* in_sizes, int n_in,
                              void* d_out, int out_size, void* d_ws, size_t ws_size,
                              hipStream_t stream) {
  (void)in_sizes; (void)n_in; (void)out_size; (void)ws_size;
  const float* feat   = (const float*)d_in[0];
  const float* hidden = (const float*)d_in[1];
  const float* W1  = (const float*)d_in[2];
  const float* b1  = (const float*)d_in[3];
  const float* W2  = (const float*)d_in[4];
  const float* b2  = (const float*)d_in[5];
  const float* V   = (const float*)d_in[6];
  const float* bV  = (const float*)d_in[7];
  const float* W3  = (const float*)d_in[8];
  const float* b3  = (const float*)d_in[9];
  const float* ka1 = (const float*)d_in[10];
  const float* kb1 = (const float*)d_in[11];
  const float* ka2 = (const float*)d_in[12];
  const float* kb2 = (const float*)d_in[13];

  char* ws = (char*)d_ws;
  // long-lived:
  unsigned short* W3p   = (unsigned short*)(ws);              // 2.5 MB  [0, 2621440)
  unsigned short* A2    = (unsigned short*)(ws + 2621440);    // 2.5 MB  [2621440, 5242880)
  // W1p (2 MB) with W2p contiguous right after (attn K-extension relies on this):
  unsigned short* W1p   = (unsigned short*)(ws + 5242880);    // [5242880, 7340032)
  unsigned short* W2p   = (unsigned short*)(ws + 7340032);    // [7340032, 7864320)
  float*          gauss = (float*)(ws + 9437184);             // 128 KB
  // part overlaps W1p/W2p (dead by final GEMM): 4 MB
  float*          part  = (float*)(ws + 5242880);

  float* out    = (float*)d_out;
  float* aw_out = out + 512 * 512;

  pack_all<<<dim3(80, 8, 3), 256, 0, stream>>>(W1, W2, W3, W1p, W2p, W3p);
  prep_batch<<<512, 512, 0, stream>>>(hidden, ka1, kb1, ka2, kb2, gauss, A2);
  attn_main<<<512, 256, 0, stream>>>(feat, W1p, b1, b2, hidden, V, bV, gauss, aw_out, A2);
  gemm64d<<<dim3(8, 8, 4), 256, 0, stream>>>(A2, 2560, 80, 20, W3p, nullptr, part);
  reduce4<<<256, 256, 0, stream>>>(part, b3, out);
}

// Round 6
// 523.686 us; speedup vs baseline: 1.0664x; 1.0664x over previous
//
#include <hip/hip_runtime.h>

typedef __bf16 bf16x8 __attribute__((ext_vector_type(8)));
typedef float f32x4 __attribute__((ext_vector_type(4)));

// Raw barrier WITHOUT the vmcnt(0) drain that __syncthreads() emits.
#define FAST_BARRIER()                                        \
  do {                                                        \
    asm volatile("s_waitcnt lgkmcnt(0)" ::: "memory");        \
    __builtin_amdgcn_s_barrier();                             \
    asm volatile("" ::: "memory");                            \
  } while (0)

static __device__ __forceinline__ unsigned short f2bf(float f) {
  union { float fv; unsigned u; } v; v.fv = f;
  unsigned u = v.u;
  u += 0x7fffu + ((u >> 16) & 1u);   // round-to-nearest-even
  return (unsigned short)(u >> 16);
}

static __device__ __forceinline__ float fast_tanh(float x) {
  x = fminf(fmaxf(x, -15.f), 15.f);
  float ex = __expf(2.f * x);
  return (ex - 1.f) / (ex + 1.f);
}

// ---- pack W (K x 512) fp32 row-major -> bf16 fragment-major P[k/8][n][k%8] ----
__global__ __launch_bounds__(256) void pack_all(
    const float* __restrict__ W1, const float* __restrict__ W2,
    const float* __restrict__ W3,
    unsigned short* __restrict__ W1p, unsigned short* __restrict__ W2p,
    unsigned short* __restrict__ W3p) {
  __shared__ float tile[32][65];
  const int N = 512;
  const float* W; unsigned short* P; int nk;
  if (blockIdx.z == 0)      { W = W1; P = W1p; nk = 64; }
  else if (blockIdx.z == 1) { W = W2; P = W2p; nk = 16; }
  else                      { W = W3; P = W3p; nk = 80; }
  if ((int)blockIdx.x >= nk) return;
  int k0 = blockIdx.x * 32, n0 = blockIdx.y * 64;
  int t = threadIdx.x;
  int nn = t & 63, kkb = t >> 6;
#pragma unroll
  for (int i = 0; i < 8; ++i) {
    int kk = kkb + i * 4;
    tile[kk][nn] = W[(size_t)(k0 + kk) * N + n0 + nn];
  }
  __syncthreads();
#pragma unroll
  for (int i = 0; i < 8; ++i) {
    int e = t + i * 256;                 // 0..2047
    int k8 = e & 7, n = (e >> 3) & 63, c = e >> 9;   // c = k-chunk within 32 (0..3)
    size_t dst = (size_t)((k0 >> 3) + c) * 4096 + (size_t)(n0 + n) * 8 + k8;
    P[dst] = f2bf(tile[c * 8 + k8][n]);
  }
}

// ---- per-batch prep (512 thr): gauss mask, tanh(hidden) into A2 cols 2048..2559 ----
__global__ __launch_bounds__(512) void prep_batch(
    const float* __restrict__ hidden,
    const float* __restrict__ ka1, const float* __restrict__ kb1,
    const float* __restrict__ ka2, const float* __restrict__ kb2,
    float* __restrict__ gauss,
    unsigned short* __restrict__ A2) {
  int b = blockIdx.x, t = threadIdx.x;
  __shared__ float hl[512];
  __shared__ float part[512];
  __shared__ float tt[128];
  __shared__ float pp[128];
  {
    float v = hidden[b * 512 + t];
    hl[t] = v;
    A2[(size_t)b * 2560 + 2048 + t] = f2bf(tanhf(v));
  }
  __syncthreads();
  {
    // 4-way split of the 512-MAC dot: ka1 for t<256, ka2 for t>=256
    const float* ka = (t < 256) ? ka1 : ka2;   // (512, 64)
    int lp = t & 63;
    int h0 = ((t >> 6) & 3) * 128;
    float s0 = 0.f, s1 = 0.f, s2 = 0.f, s3 = 0.f;
    for (int h = h0; h < h0 + 128; h += 4) {
      s0 += hl[h + 0] * ka[(h + 0) * 64 + lp];
      s1 += hl[h + 1] * ka[(h + 1) * 64 + lp];
      s2 += hl[h + 2] * ka[(h + 2) * 64 + lp];
      s3 += hl[h + 3] * ka[(h + 3) * 64 + lp];
    }
    part[t] = (s0 + s1) + (s2 + s3);
  }
  __syncthreads();
  if (t < 128) {
    int base = ((t >= 64) ? 256 : 0) + (t & 63);
    tt[t] = tanhf(part[base] + part[base + 64] + part[base + 128] + part[base + 192]);
  }
  __syncthreads();
  if (t < 128) {
    const float* kb = (t < 64) ? kb1 : kb2;   // (64, 64)
    const float* ts = (t < 64) ? tt : tt + 64;
    int l = t & 63;
    float s = 0.f;
    for (int j = 0; j < 64; ++j) s += ts[j] * kb[j * 64 + l];
    pp[t] = 8.0f / (1.0f + expf(-s));         // sigmoid * sqrt(64)
  }
  __syncthreads();
  if (t < 64) {
    float fi = (float)(t + 1);
    float r = floorf(fi * 0.125f);
    float c = floorf(fmodf(fi, 8.0f)) - 1.0f;
    float dr = r - pp[t], dc = c - pp[64 + t];
    gauss[b * 64 + t] = expf(-2.0f * (dr * dr + dc * dc));
  }
}

// ---- 64x64-tile bf16 MFMA GEMM, B direct from L2 fragment-layout, K-split ----
__global__ __launch_bounds__(256, 4) void gemm64d(
    const unsigned short* __restrict__ A, int lda, int k8_stride, int nsteps,
    const unsigned short* __restrict__ Wp,
    const float* __restrict__ bias,
    float* __restrict__ C) {
  __shared__ unsigned short lA[64 * 40];
  int m0 = blockIdx.x * 64, n0 = blockIdx.y * 64;
  int z = blockIdx.z;
  int k8 = z * k8_stride;
  int t = threadIdx.x;
  int w = t >> 6, lane = t & 63, q = lane >> 4, l15 = lane & 15;
  f32x4 acc[4] = {};
  int arow = t >> 2, achk = (t & 3) * 8;
  const unsigned short* pA = A + (size_t)(m0 + arow) * lda + (size_t)k8 * 8 + achk;
  const unsigned short* pB = Wp + ((size_t)(k8 + q) * 512 + n0 + w * 16 + l15) * 8;
  int4 av = *(const int4*)(pA);
  int4 bv = *(const int4*)(pB);
  for (int ks = 0; ks < nsteps; ++ks) {
    FAST_BARRIER();
    *(int4*)(lA + arow * 40 + achk) = av;
    FAST_BARRIER();
    int ksn = (ks + 1 < nsteps) ? ks + 1 : ks;
    av = *(const int4*)(pA + ksn * 32);
    int4 bn = *(const int4*)(pB + (size_t)ksn * 16384);
    bf16x8 bf = *(const bf16x8*)&bv;
#pragma unroll
    for (int mt = 0; mt < 4; ++mt) {
      bf16x8 af = *(const bf16x8*)(lA + (mt * 16 + l15) * 40 + q * 8);
      acc[mt] = __builtin_amdgcn_mfma_f32_16x16x32_bf16(af, bf, acc[mt], 0, 0, 0);
    }
    bv = bn;
  }
  int col = n0 + w * 16 + l15;
  if (bias) {
    float bsv = bias[col];
#pragma unroll
    for (int mt = 0; mt < 4; ++mt)
#pragma unroll
      for (int j = 0; j < 4; ++j)
        C[(size_t)(m0 + mt * 16 + q * 4 + j) * 512 + col] = acc[mt][j] + bsv;
  } else {
    float* Cp = C + (size_t)z * 262144;
#pragma unroll
    for (int mt = 0; mt < 4; ++mt)
#pragma unroll
      for (int j = 0; j < 4; ++j)
        Cp[(size_t)(m0 + mt * 16 + q * 4 + j) * 512 + col] = acc[mt][j];
  }
}

// ---- reduce 4 K-split partials + bias -> out ----
__global__ __launch_bounds__(256) void reduce4(const float* __restrict__ part,
                                               const float* __restrict__ b3,
                                               float* __restrict__ out) {
  int i = blockIdx.x * 256 + threadIdx.x;   // float4 index, 65536 total
  int base = i * 4;
  int n = base & 511;
  float4 p0 = *(const float4*)(part + base);
  float4 p1 = *(const float4*)(part + 262144 + base);
  float4 p2 = *(const float4*)(part + 524288 + base);
  float4 p3 = *(const float4*)(part + 786432 + base);
  float4 bv = *(const float4*)(b3 + n);
  float4 r;
  r.x = p0.x + p1.x + p2.x + p3.x + bv.x;
  r.y = p0.y + p1.y + p2.y + p3.y + bv.y;
  r.z = p0.z + p1.z + p2.z + p3.z + bv.z;
  r.w = p0.w + p1.w + p2.w + p3.w + bv.w;
  *(float4*)(out + base) = r;
}

// ---- fused attn v3: LDS-staged (r2-verified structure), 8 waves, acc[4][4] ----
// one block per batch, 512 thr (8 waves). Wave w owns U-cols [w*64, w*64+64).
// K = 80 phases of 32: 0..63 = feat@W1, 64..79 = h@W2 (hidden chunk staged into
// the LDS tile broadcast across all 64 rows -> identical MFMA path; W2p sits
// contiguously after W1p). acc[4][4]=64 regs; __launch_bounds__(512,4) targets
// <=128 VGPR so 2 blocks/CU = 16 waves/CU (2x round-2 occupancy).
__global__ __launch_bounds__(512, 4) void attn_main(
    const float* __restrict__ feat,          // (B*64, 2048) fp32
    const unsigned short* __restrict__ W1p,  // bf16 fragment-major, W2p contiguous after
    const float* __restrict__ b1,
    const float* __restrict__ b2,
    const float* __restrict__ hidden,        // (512, 512) fp32
    const float* __restrict__ V,
    const float* __restrict__ bVp,
    const float* __restrict__ gauss,
    float* __restrict__ aw_out,
    unsigned short* __restrict__ A2) {
  __shared__ unsigned short lA[2][64 * 40];  // 10.2 KB
  __shared__ float red[64 * 8];
  __shared__ float awl[64];
  int b = blockIdx.x, t = threadIdx.x;
  int w = t >> 6, lane = t & 63, q = lane >> 4, l15 = lane & 15;
  f32x4 acc[4][4] = {};
  int row0 = t >> 3, ch0 = t & 7;            // A stage: 1 float4 per thread
  const float* Ab = feat + (size_t)b * (64 * 2048);
  const float* pA0 = Ab + row0 * 2048 + ch0 * 4;
  const float* pH  = hidden + b * 512 + ch0 * 4;   // broadcast rows for phases 64..79
  const unsigned short* pB = W1p + ((size_t)q * 512 + w * 64 + l15) * 8;
  int wA = row0 * 40 + ch0 * 4;

  auto ldA = [&](int p) -> float4 {
    if (p < 64) return *(const float4*)(pA0 + p * 32);
    int pp = (p < 80) ? p : 79;
    return *(const float4*)(pH + (pp - 64) * 32);
  };
  auto stage = [&](int buf, const float4& x) {
    ushort4 u;
    u.x = f2bf(x.x); u.y = f2bf(x.y); u.z = f2bf(x.z); u.w = f2bf(x.w);
    *(ushort4*)(&lA[buf][wA]) = u;
  };
  auto ldB = [&](int p, int4* dst) {
    const unsigned short* bp = pB + (size_t)((p < 80) ? p : 79) * 16384;
#pragma unroll
    for (int nt = 0; nt < 4; ++nt) dst[nt] = *(const int4*)(bp + nt * 128);
  };
  auto mmaStep = [&](int buf, const int4* B) {
    __builtin_amdgcn_s_setprio(1);
#pragma unroll
    for (int mt = 0; mt < 4; ++mt) {
      bf16x8 af = *(const bf16x8*)(&lA[buf][(mt * 16 + l15) * 40 + q * 8]);
#pragma unroll
      for (int nt = 0; nt < 4; ++nt)
        acc[mt][nt] = __builtin_amdgcn_mfma_f32_16x16x32_bf16(
            af, *(const bf16x8*)&B[nt], acc[mt][nt], 0, 0, 0);
    }
    __builtin_amdgcn_s_setprio(0);
  };

  int4 bc[4], bn[4];
  float4 a0, a1;
  // preamble: stage phase 0, prefetch phase 1
  a0 = ldA(0); ldB(0, bc);
  stage(0, a0);
  a1 = ldA(1); ldB(1, bn);
  FAST_BARRIER();

  for (int s2 = 0; s2 < 40; ++s2) {
    int p = 2 * s2;
    // even phase p: compute buf0 with B(p); stage A(p+1)->buf1; fetch A(p+2), B(p+2)
    stage(1, a1);
    a0 = ldA(p + 2);
    mmaStep(0, bc);
    ldB(p + 2, bc);
    FAST_BARRIER();
    // odd phase p+1: compute buf1 with B(p+1); stage A(p+2)->buf0; fetch A(p+3), B(p+3)
    stage(0, a0);
    a1 = ldA(p + 3);
    mmaStep(1, bn);
    ldB(p + 3, bn);
    FAST_BARRIER();
  }

  // epilogue operands (tiny, L2-resident)
  float vv[4], bb[4];
#pragma unroll
  for (int nt = 0; nt < 4; ++nt) {
    int u = w * 64 + nt * 16 + l15;
    vv[nt] = V[u];
    bb[nt] = b1[u] + b2[u];
  }
  float gs = (t < 64) ? gauss[b * 64 + t] : 0.f;
  float bV0 = bVp[0];

  // logits = sum_u tanh(acc + b1 + b2) * V[u]
#pragma unroll
  for (int mt = 0; mt < 4; ++mt) {
#pragma unroll
    for (int j = 0; j < 4; ++j) {
      float p = 0.f;
#pragma unroll
      for (int nt = 0; nt < 4; ++nt)
        p += fast_tanh(acc[mt][nt][j] + bb[nt]) * vv[nt];
      p += __shfl_xor(p, 1);
      p += __shfl_xor(p, 2);
      p += __shfl_xor(p, 4);
      p += __shfl_xor(p, 8);
      if (l15 == 0) red[(mt * 16 + q * 4 + j) * 8 + w] = p;
    }
  }
  __syncthreads();
  if (t < 64) {   // wave 0: softmax over L=64 + gaussian mask
    float s = bV0;
#pragma unroll
    for (int wi = 0; wi < 8; ++wi) s += red[t * 8 + wi];
    float mx = s;
#pragma unroll
    for (int o = 1; o < 64; o <<= 1) mx = fmaxf(mx, __shfl_xor(mx, o));
    float e = __expf(s - mx);
    float sm = e;
#pragma unroll
    for (int o = 1; o < 64; o <<= 1) sm += __shfl_xor(sm, o);
    float a = (e / sm) * gs;
    awl[t] = a;
    aw_out[b * 64 + t] = a;
  }
  __syncthreads();
  // context: 4 cols per thread; write tanh(ctx) bf16 into A2
  float4 c0 = make_float4(0.f, 0.f, 0.f, 0.f);
  const float* pF = Ab + t * 4;
  for (int l = 0; l < 64; ++l) {
    float a = awl[l];
    float4 f0 = *(const float4*)(pF + l * 2048);
    c0.x += a * f0.x; c0.y += a * f0.y; c0.z += a * f0.z; c0.w += a * f0.w;
  }
  ushort4 o0;
  o0.x = f2bf(fast_tanh(c0.x)); o0.y = f2bf(fast_tanh(c0.y));
  o0.z = f2bf(fast_tanh(c0.z)); o0.w = f2bf(fast_tanh(c0.w));
  *(ushort4*)(A2 + (size_t)b * 2560 + t * 4) = o0;
}

extern "C" void kernel_launch(void* const* d_in, const int* in_sizes, int n_in,
                              void* d_out, int out_size, void* d_ws, size_t ws_size,
                              hipStream_t stream) {
  (void)in_sizes; (void)n_in; (void)out_size; (void)ws_size;
  const float* feat   = (const float*)d_in[0];
  const float* hidden = (const float*)d_in[1];
  const float* W1  = (const float*)d_in[2];
  const float* b1  = (const float*)d_in[3];
  const float* W2  = (const float*)d_in[4];
  const float* b2  = (const float*)d_in[5];
  const float* V   = (const float*)d_in[6];
  const float* bV  = (const float*)d_in[7];
  const float* W3  = (const float*)d_in[8];
  const float* b3  = (const float*)d_in[9];
  const float* ka1 = (const float*)d_in[10];
  const float* kb1 = (const float*)d_in[11];
  const float* ka2 = (const float*)d_in[12];
  const float* kb2 = (const float*)d_in[13];

  char* ws = (char*)d_ws;
  // long-lived:
  unsigned short* W3p   = (unsigned short*)(ws);              // 2.5 MB  [0, 2621440)
  unsigned short* A2    = (unsigned short*)(ws + 2621440);    // 2.5 MB  [2621440, 5242880)
  // W1p (2 MB) with W2p contiguous right after (attn K-extension relies on this):
  unsigned short* W1p   = (unsigned short*)(ws + 5242880);    // [5242880, 7340032)
  unsigned short* W2p   = (unsigned short*)(ws + 7340032);    // [7340032, 7864320)
  float*          gauss = (float*)(ws + 9437184);             // 128 KB
  // part overlaps W1p/W2p (dead by final GEMM): 4 MB
  float*          part  = (float*)(ws + 5242880);

  float* out    = (float*)d_out;
  float* aw_out = out + 512 * 512;

  pack_all<<<dim3(80, 8, 3), 256, 0, stream>>>(W1, W2, W3, W1p, W2p, W3p);
  prep_batch<<<512, 512, 0, stream>>>(hidden, ka1, kb1, ka2, kb2, gauss, A2);
  attn_main<<<512, 512, 0, stream>>>(feat, W1p, b1, b2, hidden, V, bV, gauss, aw_out, A2);
  gemm64d<<<dim3(8, 8, 4), 256, 0, stream>>>(A2, 2560, 80, 20, W3p, nullptr, part);
  reduce4<<<256, 256, 0, stream>>>(part, b3, out);
}